// Round 9
// baseline (52.458 us; speedup 1.0000x reference)
//
#include <hip/hip_runtime.h>
#include <hip/hip_cooperative_groups.h>

#define L_SIG   48000
#define WLEN    1025
#define FPB     128                 // frames per block: lane owns frames {lane, lane+64}
#define WAVES   8
#define THREADS 512
#define NQ      289                 // float4 quads per signal: 4*289 = 1156 elements
#define SEGL    (4 * NQ)            // 1156 ; segl[m] = x[ga + m], seg[j] = segl[j+3]
#define JMAX    1152                // samples j in [0, JMAX) feed frame taps
#define NBLK    (L_SIG / FPB)       // 375

#if __has_builtin(__builtin_amdgcn_exp2f)
#define EXP2F(x) __builtin_amdgcn_exp2f(x)
#else
#define EXP2F(x) __exp2f(x)
#endif
#if __has_builtin(__builtin_amdgcn_rcpf)
#define RCPF(x) __builtin_amdgcn_rcpf(x)
#else
#define RCPF(x) (1.0f / (x))
#endif

// DPP add step: invalid/masked source lanes contribute 0 (old = 0, bound_ctrl off).
template <int CTRL, int RMASK>
__device__ __forceinline__ float dpp_add(float x) {
    int t = __builtin_amdgcn_update_dpp(0, __float_as_int(x), CTRL, RMASK, 0xF, false);
    return x + __int_as_float(t);
}
template <int CTRL, int RMASK>
__device__ __forceinline__ float dpp_max(float x) {
    int t = __builtin_amdgcn_update_dpp(0, __float_as_int(x), CTRL, RMASK, 0xF, false);
    return fmaxf(x, __int_as_float(t));   // old = 0, fine for nonneg values
}
// 64-lane inclusive prefix sum
__device__ __forceinline__ float wave_scan_incl(float x) {
    x = dpp_add<0x111, 0xF>(x);  // row_shr:1
    x = dpp_add<0x112, 0xF>(x);  // row_shr:2
    x = dpp_add<0x114, 0xF>(x);  // row_shr:4
    x = dpp_add<0x118, 0xF>(x);  // row_shr:8
    x = dpp_add<0x142, 0xA>(x);  // row_bcast:15 -> rows 1,3
    x = dpp_add<0x143, 0xC>(x);  // row_bcast:31 -> rows 2,3
    return x;
}
__device__ __forceinline__ float wave_sum_bcast(float x) {
    return __int_as_float(__builtin_amdgcn_readlane(
        __float_as_int(wave_scan_incl(x)), 63));
}
__device__ __forceinline__ float wave_max_bcast(float x) {
    x = dpp_max<0x111, 0xF>(x);
    x = dpp_max<0x112, 0xF>(x);
    x = dpp_max<0x114, 0xF>(x);
    x = dpp_max<0x118, 0xF>(x);
    x = dpp_max<0x142, 0xA>(x);
    x = dpp_max<0x143, 0xC>(x);
    return __int_as_float(__builtin_amdgcn_readlane(__float_as_int(x), 63));
}
__device__ __forceinline__ float rl63(float x) {
    return __int_as_float(__builtin_amdgcn_readlane(__float_as_int(x), 63));
}
// sigma(a) - 1 where sigma = 1/(1 + 2^a); == 0 exactly in f32 when a <= -25
__device__ __forceinline__ float sigm1(float a) {
    float e = EXP2F(a);
    return RCPF(1.0f + e) - 1.0f;
}

__global__ __launch_bounds__(THREADS) void soft_edp_kernel(
    const float* __restrict__ xp, const float* __restrict__ xt,
    const float* __restrict__ win, float* __restrict__ wsbuf,
    float* __restrict__ out)
{
    __shared__ __align__(16) float segp[SEGL];
    __shared__ __align__(16) float segt[SEGL];
    __shared__ float redv[WAVES][5];
    __shared__ float kl2s[FPB], cps[FPB], cts[FPB];
    __shared__ float iw[FPB];
    __shared__ float partp[WAVES][FPB], partt[WAVES][FPB];
    __shared__ float ddsh[2];
    __shared__ float tsh;
    __shared__ int   ncand_sh;
    __shared__ int   cand[JMAX];

    const int tid  = threadIdx.x;
    const int lane = tid & 63;
    const int wv   = tid >> 6;
    const int l0   = blockIdx.x * FPB;
    const int g0   = l0 - WLEN;         // seg[j] = x[g0+j]
    const int ga   = g0 - 3;            // g0 ≡ 3 (mod 4) -> ga 16B-aligned
    const bool early = (l0 <= 1024);    // blocks 0..8: padding present, scalar path
    int n_min = 898 - l0; if (n_min < 0) n_min = 0;   // min pad-tap count in block

    if (tid == 0) ncand_sh = 0;

    // ---- Phase A: stage segment (fast: float4 + fused moments; early: scalar)
    float sp = 0.f, ssp = 0.f, st = 0.f, sst = 0.f, pb = 0.f;
    if (!early) {
        if (tid < NQ) {                       // y_pred quads
            float4 v = ((const float4*)(xp + ga))[tid];
            ((float4*)segp)[tid] = v;
            const float vv[4] = {v.x, v.y, v.z, v.w};
            int m0 = 4 * tid;
#pragma unroll
            for (int r = 0; r < 4; ++r) {
                int m = m0 + r;               // moment window: m in [3, 1028)
                if (m >= 3 && m < 1028) { float a = vv[r]; sp += a; ssp = fmaf(a, a, ssp); }
            }
        }
        if (tid >= THREADS - NQ) {            // y_true quads
            int q = tid - (THREADS - NQ);
            float4 v = ((const float4*)(xt + ga))[q];
            ((float4*)segt)[q] = v;
            const float vv[4] = {v.x, v.y, v.z, v.w};
            int m0 = 4 * q;
#pragma unroll
            for (int r = 0; r < 4; ++r) {
                int m = m0 + r;
                if (m >= 3 && m < 1028) { float a = vv[r]; st += a; sst = fmaf(a, a, sst); }
            }
        }
    } else {
        for (int m = tid; m < SEGL; m += THREADS) {
            int g = ga + m;
            bool ok = (g >= 0) && (g < L_SIG);
            segp[m] = ok ? xp[g] : 0.0f;
            segt[m] = ok ? xt[g] : 0.0f;
        }
    }
    __syncthreads();

    // ---- Phase B (early only): moments from LDS + pad-base window sum
    if (early) {
        for (int j = tid; j < WLEN; j += THREADS) {
            float a = segp[j + 3], b = segt[j + 3];
            sp += a; ssp = fmaf(a, a, ssp);
            st += b; sst = fmaf(b, b, sst);
        }
        for (int k = tid; k < n_min; k += THREADS) pb += win[k];
    }
    sp  = wave_sum_bcast(sp);
    ssp = wave_sum_bcast(ssp);
    st  = wave_sum_bcast(st);
    sst = wave_sum_bcast(sst);
    if (early) pb = wave_sum_bcast(pb);
    if (lane == 0) {
        redv[wv][0] = sp; redv[wv][1] = ssp;
        redv[wv][2] = st; redv[wv][3] = sst;
        redv[wv][4] = pb;
    }
    __syncthreads();

    // ---- Phase C: wave 0 = chained 2x64 std scan + threshold; wave 1 = pad prefix
    if (wv == 0) {
        float base_sp = 0.f, base_ssp = 0.f, base_st = 0.f, base_sst = 0.f;
#pragma unroll
        for (int w = 0; w < WAVES; ++w) {
            base_sp  += redv[w][0]; base_ssp += redv[w][1];
            base_st  += redv[w][2]; base_sst += redv[w][3];
        }
        const float LOG2E = 1.4426950408889634f;
        float mxl = 0.f;
#pragma unroll
        for (int h = 0; h < 2; ++h) {
            int i = lane + 64 * h;
            float p0 = segp[i + 3], p1 = segp[i + WLEN + 3];
            float t0 = segt[i + 3], t1 = segt[i + WLEN + 3];
            float dsp  = p1 - p0;
            float dssp = fmaf(p1, p1, -(p0 * p0));
            float dst_ = t1 - t0;
            float dsst = fmaf(t1, t1, -(t0 * t0));
            float isp  = wave_scan_incl(dsp);
            float issp = wave_scan_incl(dssp);
            float ist  = wave_scan_incl(dst_);
            float isst = wave_scan_incl(dsst);
            float sum_p = base_sp  + (isp  - dsp);
            float ss_p  = base_ssp + (issp - dssp);
            float sum_t = base_st  + (ist  - dst_);
            float ss_t  = base_sst + (isst - dsst);
            float varp = (ss_p - sum_p * sum_p * (1.0f / WLEN)) * (1.0f / (WLEN - 1));
            float vart = (ss_t - sum_t * sum_t * (1.0f / WLEN)) * (1.0f / (WLEN - 1));
            float stdp = sqrtf(fmaxf(varp, 0.f));
            float stdt = sqrtf(fmaxf(vart, 0.f));
            float kappa = 100.0f + (99900.0f / 48000.0f) * (float)(l0 + i);
            kl2s[i] = kappa * LOG2E;
            cps[i]  = stdp * LOG2E;
            cts[i]  = stdt * LOG2E;
            mxl = fmaxf(mxl, fmaxf(stdp, stdt));
            base_sp  += rl63(isp);
            base_ssp += rl63(issp);
            base_st  += rl63(ist);
            base_sst += rl63(isst);
        }
        float mx = wave_max_bcast(mxl);
        if (lane == 0) {
            float kmin = 100.0f + (99900.0f / 48000.0f) * (float)l0;
            // tap escapes saturation iff |v| <= (std + 24*ln2)/kappa ; superset
            tsh = (mx + 17.0f) * 1.001f / kmin;
        }
    } else if (wv == 1 && early) {
        float carry = 0.f;
#pragma unroll
        for (int h = 0; h < 2; ++h) {
            int kk = n_min + 64 * h + lane;
            float wval = (kk <= 1024) ? win[kk] : 0.f;
            float I = wave_scan_incl(wval) + carry;   // I[m] = sum w[n_min..n_min+m]
            iw[64 * h + lane] = I;
            carry = rl63(I);
        }
    }
    __syncthreads();

    // ---- Phase D: candidate compaction (samples that can escape saturation)
    {
        const float T = tsh;
        const int npad = early ? (1025 - l0) : 0;
        for (int j = tid; j < JMAX; j += THREADS) {
            bool flag = (j >= npad) &&
                        ((fabsf(segp[j + 3]) <= T) || (fabsf(segt[j + 3]) <= T));
            unsigned long long m = __ballot(flag);
            int cnt = __popcll(m);
            int base = 0;
            if (lane == 0 && cnt) base = atomicAdd(&ncand_sh, cnt);
            base = __shfl(base, 0);
            if (flag) {
                int pos = base + __popcll(m & ((1ull << lane) - 1ull));
                cand[pos] = j;
            }
        }
    }
    __syncthreads();

    // ---- Phase E: correction sweep; lane owns frames A=lane, B=lane+64
    const float kl2A = kl2s[lane],      cpA = cps[lane],      ctA = cts[lane];
    const float kl2B = kl2s[lane + 64], cpB = cps[lane + 64], ctB = cts[lane + 64];
    float aPA = 0.f, aTA = 0.f, aPB = 0.f, aTB = 0.f;   // sum of (sigma-1)*w
    const int nc = ncand_sh;
    for (int c = wv; c < nc; c += WAVES) {
        int j = cand[c];                        // wave-uniform LDS broadcast
        float avp = fabsf(segp[j + 3]), avt = fabsf(segt[j + 3]);
        int kA = j - lane;                      // tap index for frame A
        if ((unsigned)kA < 1025u) {
            float wk = win[kA];                 // stride-1 across lanes, L1-hit
            aPA = fmaf(sigm1(fmaf(-avp, kl2A, cpA)), wk, aPA);
            aTA = fmaf(sigm1(fmaf(-avt, kl2A, ctA)), wk, aTA);
        }
        int kB = kA - 64;                       // tap index for frame B
        if ((unsigned)kB < 1025u) {
            float wk = win[kB];
            aPB = fmaf(sigm1(fmaf(-avp, kl2B, cpB)), wk, aPB);
            aTB = fmaf(sigm1(fmaf(-avt, kl2B, ctB)), wk, aTB);
        }
    }
    partp[wv][lane]      = aPA;
    partp[wv][lane + 64] = aPB;
    partt[wv][lane]      = aTA;
    partt[wv][lane + 64] = aTB;
    __syncthreads();

    // ---- Phase F: combine, add pad term, square differences -> per-block partial
    if (wv < 2) {
        int i = lane + 64 * wv;
        float SP = 0.f, ST = 0.f;
#pragma unroll
        for (int w = 0; w < WAVES; ++w) {
            SP += partp[w][i];
            ST += partt[w][i];
        }
        if (early) {
            float padbase = 0.f;
#pragma unroll
            for (int w = 0; w < WAVES; ++w) padbase += redv[w][4];
            int n_f = 1025 - l0 - i;            // zero-pad tap count for frame l0+i
            float pw = 0.f;
            if (n_f >= 1) {
                int lf = n_f - n_min;           // in [0, 127]
                pw = padbase + ((lf >= 1) ? iw[lf - 1] : 0.f);
            }
            SP = fmaf(sigm1(cps[i]), pw, SP);   // v = 0 taps: a = std*log2e
            ST = fmaf(sigm1(cts[i]), pw, ST);
        }
        float d  = SP - ST;                     // window-sum term cancels exactly
        float dd = wave_sum_bcast(d * d);
        if (lane == 0) ddsh[wv] = dd;
    }
    __syncthreads();
    if (tid == 0) wsbuf[blockIdx.x] = ddsh[0] + ddsh[1];   // plain store, no atomics

    // ---- Phase G: grid-wide barrier, then block 0 does the deterministic reduce
    cooperative_groups::this_grid().sync();
    if (blockIdx.x == 0) {
        float v = (tid < NBLK) ? wsbuf[tid] : 0.f;
        v = wave_sum_bcast(v);
        if (lane == 0) redv[wv][0] = v;         // redv reusable after grid sync
        __syncthreads();
        if (tid == 0) {
            float t = 0.f;
#pragma unroll
            for (int w = 0; w < WAVES; ++w) t += redv[w][0];
            const float scale =
                (float)(1.0 / (48000.0 * 0.3173105078629141 * 0.3173105078629141));
            out[0] = t * scale;                 // unconditional write: no memset needed
        }
    }
}

extern "C" void kernel_launch(void* const* d_in, const int* in_sizes, int n_in,
                              void* d_out, int out_size, void* d_ws, size_t ws_size,
                              hipStream_t stream) {
    const float* xp  = (const float*)d_in[0];  // y_pred, 48000 f32
    const float* xt  = (const float*)d_in[1];  // y_true, 48000 f32
    const float* win = (const float*)d_in[2];  // window, 1025 f32
    float* out = (float*)d_out;
    float* wsb = (float*)d_ws;                 // NBLK f32 partials (overwritten each call)

    void* args[] = {(void*)&xp, (void*)&xt, (void*)&win, (void*)&wsb, (void*)&out};
    hipLaunchCooperativeKernel(reinterpret_cast<void*>(soft_edp_kernel),
                               dim3(NBLK), dim3(THREADS), args, 0, stream);
}

// Round 10
// 12.118 us; speedup vs baseline: 4.3288x; 4.3288x over previous
//
#include <hip/hip_runtime.h>

#define L_SIG   48000
#define WLEN    1025
#define FPB     192                 // frames per block: lane owns {lane, lane+64, lane+128}
#define WAVES   8
#define THREADS 512
#define NQ      305                 // float4 quads per signal: 4*305 = 1220 elements
#define SEGL    (4 * NQ)            // 1220 ; segl[m] = x[ga + m], seg[j] = segl[j+3]
#define JMAX    1216                // samples j in [0, JMAX) feed frame taps
#define NBLK    (L_SIG / FPB)       // 250  -> at most 1 block per CU
#define NH      3                   // 64-frame groups per block

#if __has_builtin(__builtin_amdgcn_exp2f)
#define EXP2F(x) __builtin_amdgcn_exp2f(x)
#else
#define EXP2F(x) __exp2f(x)
#endif
#if __has_builtin(__builtin_amdgcn_rcpf)
#define RCPF(x) __builtin_amdgcn_rcpf(x)
#else
#define RCPF(x) (1.0f / (x))
#endif

// DPP add step: invalid/masked source lanes contribute 0 (old = 0, bound_ctrl off).
template <int CTRL, int RMASK>
__device__ __forceinline__ float dpp_add(float x) {
    int t = __builtin_amdgcn_update_dpp(0, __float_as_int(x), CTRL, RMASK, 0xF, false);
    return x + __int_as_float(t);
}
template <int CTRL, int RMASK>
__device__ __forceinline__ float dpp_max(float x) {
    int t = __builtin_amdgcn_update_dpp(0, __float_as_int(x), CTRL, RMASK, 0xF, false);
    return fmaxf(x, __int_as_float(t));   // old = 0, fine for nonneg values
}
// 64-lane inclusive prefix sum
__device__ __forceinline__ float wave_scan_incl(float x) {
    x = dpp_add<0x111, 0xF>(x);  // row_shr:1
    x = dpp_add<0x112, 0xF>(x);  // row_shr:2
    x = dpp_add<0x114, 0xF>(x);  // row_shr:4
    x = dpp_add<0x118, 0xF>(x);  // row_shr:8
    x = dpp_add<0x142, 0xA>(x);  // row_bcast:15 -> rows 1,3
    x = dpp_add<0x143, 0xC>(x);  // row_bcast:31 -> rows 2,3
    return x;
}
__device__ __forceinline__ float wave_sum_bcast(float x) {
    return __int_as_float(__builtin_amdgcn_readlane(
        __float_as_int(wave_scan_incl(x)), 63));
}
__device__ __forceinline__ float wave_max_bcast(float x) {
    x = dpp_max<0x111, 0xF>(x);
    x = dpp_max<0x112, 0xF>(x);
    x = dpp_max<0x114, 0xF>(x);
    x = dpp_max<0x118, 0xF>(x);
    x = dpp_max<0x142, 0xA>(x);
    x = dpp_max<0x143, 0xC>(x);
    return __int_as_float(__builtin_amdgcn_readlane(__float_as_int(x), 63));
}
__device__ __forceinline__ float rl63(float x) {
    return __int_as_float(__builtin_amdgcn_readlane(__float_as_int(x), 63));
}
// sigma(a) - 1 where sigma = 1/(1 + 2^a); == 0 exactly in f32 when a <= -25
__device__ __forceinline__ float sigm1(float a) {
    float e = EXP2F(a);
    return RCPF(1.0f + e) - 1.0f;
}

__global__ __launch_bounds__(THREADS) void soft_edp_kernel(
    const float* __restrict__ xp, const float* __restrict__ xt,
    const float* __restrict__ win, float* __restrict__ wsbuf)
{
    __shared__ __align__(16) float segp[SEGL];
    __shared__ __align__(16) float segt[SEGL];
    __shared__ float redv[WAVES][5];
    __shared__ float kl2s[FPB], cps[FPB], cts[FPB];
    __shared__ float iw[FPB];
    __shared__ float partp[WAVES][FPB], partt[WAVES][FPB];
    __shared__ float ddsh[NH];
    __shared__ float tsh;
    __shared__ int   ncand_sh;
    __shared__ int   cand[JMAX];

    const int tid  = threadIdx.x;
    const int lane = tid & 63;
    const int wv   = tid >> 6;
    const int l0   = blockIdx.x * FPB;
    const int g0   = l0 - WLEN;         // seg[j] = x[g0+j]
    const int ga   = g0 - 3;            // g0 ≡ 3 (mod 4) -> ga 16B-aligned
    const bool early = (l0 <= 1024);    // blocks 0..5: padding present, scalar path
    int n_min = (1025 - (FPB - 1)) - l0; if (n_min < 0) n_min = 0;  // = 834 - l0

    if (tid == 0) ncand_sh = 0;

    // ---- Phase A: stage segment (fast: float4 + fused moments; early: scalar)
    float sp = 0.f, ssp = 0.f, st = 0.f, sst = 0.f, pb = 0.f;
    if (!early) {
        if (tid < NQ) {                       // y_pred quads
            float4 v = ((const float4*)(xp + ga))[tid];
            ((float4*)segp)[tid] = v;
            const float vv[4] = {v.x, v.y, v.z, v.w};
            int m0 = 4 * tid;
#pragma unroll
            for (int r = 0; r < 4; ++r) {
                int m = m0 + r;               // moment window: m in [3, 1028)
                if (m >= 3 && m < 1028) { float a = vv[r]; sp += a; ssp = fmaf(a, a, ssp); }
            }
        }
        if (tid >= THREADS - NQ) {            // y_true quads
            int q = tid - (THREADS - NQ);
            float4 v = ((const float4*)(xt + ga))[q];
            ((float4*)segt)[q] = v;
            const float vv[4] = {v.x, v.y, v.z, v.w};
            int m0 = 4 * q;
#pragma unroll
            for (int r = 0; r < 4; ++r) {
                int m = m0 + r;
                if (m >= 3 && m < 1028) { float a = vv[r]; st += a; sst = fmaf(a, a, sst); }
            }
        }
    } else {
        for (int m = tid; m < SEGL; m += THREADS) {
            int g = ga + m;
            bool ok = (g >= 0) && (g < L_SIG);
            segp[m] = ok ? xp[g] : 0.0f;
            segt[m] = ok ? xt[g] : 0.0f;
        }
    }
    __syncthreads();

    // ---- Phase B (early only): moments from LDS + pad-base window sum
    if (early) {
        for (int j = tid; j < WLEN; j += THREADS) {
            float a = segp[j + 3], b = segt[j + 3];
            sp += a; ssp = fmaf(a, a, ssp);
            st += b; sst = fmaf(b, b, sst);
        }
        for (int k = tid; k < n_min; k += THREADS) pb += win[k];
    }
    sp  = wave_sum_bcast(sp);
    ssp = wave_sum_bcast(ssp);
    st  = wave_sum_bcast(st);
    sst = wave_sum_bcast(sst);
    if (early) pb = wave_sum_bcast(pb);
    if (lane == 0) {
        redv[wv][0] = sp; redv[wv][1] = ssp;
        redv[wv][2] = st; redv[wv][3] = sst;
        redv[wv][4] = pb;
    }
    __syncthreads();

    // ---- Phase C: wave 0 = chained 3x64 std scan + threshold; wave 1 = pad prefix
    if (wv == 0) {
        float base_sp = 0.f, base_ssp = 0.f, base_st = 0.f, base_sst = 0.f;
#pragma unroll
        for (int w = 0; w < WAVES; ++w) {
            base_sp  += redv[w][0]; base_ssp += redv[w][1];
            base_st  += redv[w][2]; base_sst += redv[w][3];
        }
        const float LOG2E = 1.4426950408889634f;
        float mxl = 0.f;
#pragma unroll
        for (int h = 0; h < NH; ++h) {
            int i = lane + 64 * h;
            float p0 = segp[i + 3], p1 = segp[i + WLEN + 3];
            float t0 = segt[i + 3], t1 = segt[i + WLEN + 3];
            float dsp  = p1 - p0;
            float dssp = fmaf(p1, p1, -(p0 * p0));
            float dst_ = t1 - t0;
            float dsst = fmaf(t1, t1, -(t0 * t0));
            float isp  = wave_scan_incl(dsp);
            float issp = wave_scan_incl(dssp);
            float ist  = wave_scan_incl(dst_);
            float isst = wave_scan_incl(dsst);
            float sum_p = base_sp  + (isp  - dsp);
            float ss_p  = base_ssp + (issp - dssp);
            float sum_t = base_st  + (ist  - dst_);
            float ss_t  = base_sst + (isst - dsst);
            float varp = (ss_p - sum_p * sum_p * (1.0f / WLEN)) * (1.0f / (WLEN - 1));
            float vart = (ss_t - sum_t * sum_t * (1.0f / WLEN)) * (1.0f / (WLEN - 1));
            float stdp = sqrtf(fmaxf(varp, 0.f));
            float stdt = sqrtf(fmaxf(vart, 0.f));
            float kappa = 100.0f + (99900.0f / 48000.0f) * (float)(l0 + i);
            kl2s[i] = kappa * LOG2E;
            cps[i]  = stdp * LOG2E;
            cts[i]  = stdt * LOG2E;
            mxl = fmaxf(mxl, fmaxf(stdp, stdt));
            base_sp  += rl63(isp);
            base_ssp += rl63(issp);
            base_st  += rl63(ist);
            base_sst += rl63(isst);
        }
        float mx = wave_max_bcast(mxl);
        if (lane == 0) {
            float kmin = 100.0f + (99900.0f / 48000.0f) * (float)l0;
            // tap escapes saturation iff |v| <= (std + 24*ln2)/kappa ; superset
            tsh = (mx + 17.0f) * 1.001f / kmin;
        }
    } else if (wv == 1 && early) {
        float carry = 0.f;
#pragma unroll
        for (int h = 0; h < NH; ++h) {
            int kk = n_min + 64 * h + lane;
            float wval = (kk <= 1024) ? win[kk] : 0.f;
            float I = wave_scan_incl(wval) + carry;   // I[m] = sum w[n_min..n_min+m]
            iw[64 * h + lane] = I;
            carry = rl63(I);
        }
    }
    __syncthreads();

    // ---- Phase D: candidate compaction (samples that can escape saturation)
    {
        const float T = tsh;
        const int npad = early ? (1025 - l0) : 0;
        for (int j = tid; j < JMAX; j += THREADS) {
            bool flag = (j >= npad) &&
                        ((fabsf(segp[j + 3]) <= T) || (fabsf(segt[j + 3]) <= T));
            unsigned long long m = __ballot(flag);
            int cnt = __popcll(m);
            int base = 0;
            if (lane == 0 && cnt) base = atomicAdd(&ncand_sh, cnt);
            base = __shfl(base, 0);
            if (flag) {
                int pos = base + __popcll(m & ((1ull << lane) - 1ull));
                cand[pos] = j;
            }
        }
    }
    __syncthreads();

    // ---- Phase E: correction sweep; lane owns frames lane, lane+64, lane+128
    const float kl2A = kl2s[lane],       cpA = cps[lane],       ctA = cts[lane];
    const float kl2B = kl2s[lane + 64],  cpB = cps[lane + 64],  ctB = cts[lane + 64];
    const float kl2C = kl2s[lane + 128], cpC = cps[lane + 128], ctC = cts[lane + 128];
    float aPA = 0.f, aTA = 0.f, aPB = 0.f, aTB = 0.f, aPC = 0.f, aTC = 0.f;
    const int nc = ncand_sh;
    for (int c = wv; c < nc; c += WAVES) {
        int j = cand[c];                        // wave-uniform LDS broadcast
        float avp = fabsf(segp[j + 3]), avt = fabsf(segt[j + 3]);
        int kA = j - lane;                      // tap index for frame A
        if ((unsigned)kA < 1025u) {
            float wk = win[kA];                 // stride-1 across lanes, L1-hit
            aPA = fmaf(sigm1(fmaf(-avp, kl2A, cpA)), wk, aPA);
            aTA = fmaf(sigm1(fmaf(-avt, kl2A, ctA)), wk, aTA);
        }
        int kB = kA - 64;                       // tap index for frame B
        if ((unsigned)kB < 1025u) {
            float wk = win[kB];
            aPB = fmaf(sigm1(fmaf(-avp, kl2B, cpB)), wk, aPB);
            aTB = fmaf(sigm1(fmaf(-avt, kl2B, ctB)), wk, aTB);
        }
        int kC = kA - 128;                      // tap index for frame C
        if ((unsigned)kC < 1025u) {
            float wk = win[kC];
            aPC = fmaf(sigm1(fmaf(-avp, kl2C, cpC)), wk, aPC);
            aTC = fmaf(sigm1(fmaf(-avt, kl2C, ctC)), wk, aTC);
        }
    }
    partp[wv][lane]       = aPA;
    partp[wv][lane + 64]  = aPB;
    partp[wv][lane + 128] = aPC;
    partt[wv][lane]       = aTA;
    partt[wv][lane + 64]  = aTB;
    partt[wv][lane + 128] = aTC;
    __syncthreads();

    // ---- Phase F: combine, add pad term, square differences -> per-block partial
    if (wv < NH) {
        int i = lane + 64 * wv;
        float SP = 0.f, ST = 0.f;
#pragma unroll
        for (int w = 0; w < WAVES; ++w) {
            SP += partp[w][i];
            ST += partt[w][i];
        }
        if (early) {
            float padbase = 0.f;
#pragma unroll
            for (int w = 0; w < WAVES; ++w) padbase += redv[w][4];
            int n_f = 1025 - l0 - i;            // zero-pad tap count for frame l0+i
            float pw = 0.f;
            if (n_f >= 1) {
                int lf = n_f - n_min;           // in [0, FPB-1]
                pw = padbase + ((lf >= 1) ? iw[lf - 1] : 0.f);
            }
            SP = fmaf(sigm1(cps[i]), pw, SP);   // v = 0 taps: a = std*log2e
            ST = fmaf(sigm1(cts[i]), pw, ST);
        }
        float d  = SP - ST;                     // window-sum term cancels exactly
        float dd = wave_sum_bcast(d * d);
        if (lane == 0) ddsh[wv] = dd;
    }
    __syncthreads();
    if (tid == 0) wsbuf[blockIdx.x] = ddsh[0] + ddsh[1] + ddsh[2];  // plain store

}

// Deterministic final reduction: 1 block, reads NBLK partials, writes out.
__global__ __launch_bounds__(THREADS) void soft_edp_reduce(
    const float* __restrict__ wsbuf, float* __restrict__ out)
{
    __shared__ float acc[WAVES];
    const int tid = threadIdx.x, lane = tid & 63, wv = tid >> 6;
    float v = (tid < NBLK) ? wsbuf[tid] : 0.f;
    v = wave_sum_bcast(v);
    if (lane == 0) acc[wv] = v;
    __syncthreads();
    if (tid == 0) {
        float t = 0.f;
#pragma unroll
        for (int w = 0; w < WAVES; ++w) t += acc[w];
        const float scale =
            (float)(1.0 / (48000.0 * 0.3173105078629141 * 0.3173105078629141));
        out[0] = t * scale;                     // unconditional write: no memset needed
    }
}

extern "C" void kernel_launch(void* const* d_in, const int* in_sizes, int n_in,
                              void* d_out, int out_size, void* d_ws, size_t ws_size,
                              hipStream_t stream) {
    const float* xp  = (const float*)d_in[0];  // y_pred, 48000 f32
    const float* xt  = (const float*)d_in[1];  // y_true, 48000 f32
    const float* win = (const float*)d_in[2];  // window, 1025 f32
    float* out = (float*)d_out;
    float* wsb = (float*)d_ws;                 // NBLK f32 partials (overwritten each call)

    soft_edp_kernel<<<NBLK, THREADS, 0, stream>>>(xp, xt, win, wsb);
    soft_edp_reduce<<<1, THREADS, 0, stream>>>(wsb, out);
}

// Round 12
// 11.199 us; speedup vs baseline: 4.6843x; 1.0821x over previous
//
#include <hip/hip_runtime.h>

#define L_SIG   48000
#define WLEN    1025
#define FPB     128                 // frames per block: lane owns frames {lane, lane+64}
#define WAVES   8
#define THREADS 512
#define NQ      289                 // float4 quads per signal: 4*289 = 1156 elements
#define SEGL    (4 * NQ)            // 1156 ; segl[m] = x[ga + m], seg[j] = segl[j+3]
#define JMAX    1152                // samples j in [0, JMAX) feed frame taps
#define NBLK    (L_SIG / FPB)       // 375

#if __has_builtin(__builtin_amdgcn_exp2f)
#define EXP2F(x) __builtin_amdgcn_exp2f(x)
#else
#define EXP2F(x) __exp2f(x)
#endif
#if __has_builtin(__builtin_amdgcn_rcpf)
#define RCPF(x) __builtin_amdgcn_rcpf(x)
#else
#define RCPF(x) (1.0f / (x))
#endif

// DPP add step: invalid/masked source lanes contribute 0 (old = 0, bound_ctrl off).
template <int CTRL, int RMASK>
__device__ __forceinline__ float dpp_add(float x) {
    int t = __builtin_amdgcn_update_dpp(0, __float_as_int(x), CTRL, RMASK, 0xF, false);
    return x + __int_as_float(t);
}
template <int CTRL, int RMASK>
__device__ __forceinline__ float dpp_max(float x) {
    int t = __builtin_amdgcn_update_dpp(0, __float_as_int(x), CTRL, RMASK, 0xF, false);
    return fmaxf(x, __int_as_float(t));   // old = 0, fine for nonneg values
}
// 64-lane inclusive prefix sum
__device__ __forceinline__ float wave_scan_incl(float x) {
    x = dpp_add<0x111, 0xF>(x);  // row_shr:1
    x = dpp_add<0x112, 0xF>(x);  // row_shr:2
    x = dpp_add<0x114, 0xF>(x);  // row_shr:4
    x = dpp_add<0x118, 0xF>(x);  // row_shr:8
    x = dpp_add<0x142, 0xA>(x);  // row_bcast:15 -> rows 1,3
    x = dpp_add<0x143, 0xC>(x);  // row_bcast:31 -> rows 2,3
    return x;
}
__device__ __forceinline__ float wave_sum_bcast(float x) {
    return __int_as_float(__builtin_amdgcn_readlane(
        __float_as_int(wave_scan_incl(x)), 63));
}
__device__ __forceinline__ float wave_max_bcast(float x) {
    x = dpp_max<0x111, 0xF>(x);
    x = dpp_max<0x112, 0xF>(x);
    x = dpp_max<0x114, 0xF>(x);
    x = dpp_max<0x118, 0xF>(x);
    x = dpp_max<0x142, 0xA>(x);
    x = dpp_max<0x143, 0xC>(x);
    return __int_as_float(__builtin_amdgcn_readlane(__float_as_int(x), 63));
}
__device__ __forceinline__ float rl63(float x) {
    return __int_as_float(__builtin_amdgcn_readlane(__float_as_int(x), 63));
}
// sigma(a) - 1 where sigma = 1/(1 + 2^a); == 0 exactly in f32 when a <= -25
__device__ __forceinline__ float sigm1(float a) {
    float e = EXP2F(a);
    return RCPF(1.0f + e) - 1.0f;
}

__global__ __launch_bounds__(THREADS) void soft_edp_kernel(
    const float* __restrict__ xp, const float* __restrict__ xt,
    const float* __restrict__ win, float* __restrict__ wsbuf)
{
    __shared__ __align__(16) float segp[SEGL];
    __shared__ __align__(16) float segt[SEGL];
    __shared__ float redv[WAVES][5];
    __shared__ float kl2s[FPB], cps[FPB], cts[FPB];
    __shared__ float iw[FPB];
    __shared__ float partp[WAVES][FPB], partt[WAVES][FPB];
    __shared__ float ddsh[2];
    __shared__ float tsh;
    __shared__ int   ncand_sh;
    __shared__ int   cand[JMAX];

    const int tid  = threadIdx.x;
    const int lane = tid & 63;
    const int wv   = tid >> 6;
    const int l0   = blockIdx.x * FPB;
    const int g0   = l0 - WLEN;         // seg[j] = x[g0+j]
    const int ga   = g0 - 3;            // g0 ≡ 3 (mod 4) -> ga 16B-aligned
    const bool early = (l0 <= 1024);    // blocks 0..8: padding present, scalar path
    int n_min = 898 - l0; if (n_min < 0) n_min = 0;   // min pad-tap count in block

    if (tid == 0) ncand_sh = 0;

    // ---- Phase A: stage segment; fast path fuses moments + cross-wave redv
    //      write BEFORE the barrier (one barrier serves seg + redv).
    float sp = 0.f, ssp = 0.f, st = 0.f, sst = 0.f, pb = 0.f;
    if (!early) {
        if (tid < NQ) {                       // y_pred quads
            float4 v = ((const float4*)(xp + ga))[tid];
            ((float4*)segp)[tid] = v;
            const float vv[4] = {v.x, v.y, v.z, v.w};
            int m0 = 4 * tid;
#pragma unroll
            for (int r = 0; r < 4; ++r) {
                int m = m0 + r;               // moment window: m in [3, 1028)
                if (m >= 3 && m < 1028) { float a = vv[r]; sp += a; ssp = fmaf(a, a, ssp); }
            }
        }
        if (tid >= THREADS - NQ) {            // y_true quads
            int q = tid - (THREADS - NQ);
            float4 v = ((const float4*)(xt + ga))[q];
            ((float4*)segt)[q] = v;
            const float vv[4] = {v.x, v.y, v.z, v.w};
            int m0 = 4 * q;
#pragma unroll
            for (int r = 0; r < 4; ++r) {
                int m = m0 + r;
                if (m >= 3 && m < 1028) { float a = vv[r]; st += a; sst = fmaf(a, a, sst); }
            }
        }
        // wave-local reductions + redv store (register/DPP only, no LDS dep)
        sp  = wave_sum_bcast(sp);
        ssp = wave_sum_bcast(ssp);
        st  = wave_sum_bcast(st);
        sst = wave_sum_bcast(sst);
        if (lane == 0) {
            redv[wv][0] = sp; redv[wv][1] = ssp;
            redv[wv][2] = st; redv[wv][3] = sst;
            redv[wv][4] = 0.f;
        }
        __syncthreads();                      // seg + redv both ready
    } else {
        for (int m = tid; m < SEGL; m += THREADS) {
            int g = ga + m;
            bool ok = (g >= 0) && (g < L_SIG);
            segp[m] = ok ? xp[g] : 0.0f;
            segt[m] = ok ? xt[g] : 0.0f;
        }
        __syncthreads();
        // moments from LDS + pad-base window sum
        for (int j = tid; j < WLEN; j += THREADS) {
            float a = segp[j + 3], b = segt[j + 3];
            sp += a; ssp = fmaf(a, a, ssp);
            st += b; sst = fmaf(b, b, sst);
        }
        for (int k = tid; k < n_min; k += THREADS) pb += win[k];
        sp  = wave_sum_bcast(sp);
        ssp = wave_sum_bcast(ssp);
        st  = wave_sum_bcast(st);
        sst = wave_sum_bcast(sst);
        pb  = wave_sum_bcast(pb);
        if (lane == 0) {
            redv[wv][0] = sp; redv[wv][1] = ssp;
            redv[wv][2] = st; redv[wv][3] = sst;
            redv[wv][4] = pb;
        }
        __syncthreads();
    }

    // ---- Phase C: wave 0 = chained 2x64 std scan + threshold; wave 1 = pad prefix
    if (wv == 0) {
        float base_sp = 0.f, base_ssp = 0.f, base_st = 0.f, base_sst = 0.f;
#pragma unroll
        for (int w = 0; w < WAVES; ++w) {
            base_sp  += redv[w][0]; base_ssp += redv[w][1];
            base_st  += redv[w][2]; base_sst += redv[w][3];
        }
        const float LOG2E = 1.4426950408889634f;
        float mxl = 0.f;
#pragma unroll
        for (int h = 0; h < 2; ++h) {
            int i = lane + 64 * h;
            float p0 = segp[i + 3], p1 = segp[i + WLEN + 3];
            float t0 = segt[i + 3], t1 = segt[i + WLEN + 3];
            float dsp  = p1 - p0;
            float dssp = fmaf(p1, p1, -(p0 * p0));
            float dst_ = t1 - t0;
            float dsst = fmaf(t1, t1, -(t0 * t0));
            float isp  = wave_scan_incl(dsp);
            float issp = wave_scan_incl(dssp);
            float ist  = wave_scan_incl(dst_);
            float isst = wave_scan_incl(dsst);
            float sum_p = base_sp  + (isp  - dsp);
            float ss_p  = base_ssp + (issp - dssp);
            float sum_t = base_st  + (ist  - dst_);
            float ss_t  = base_sst + (isst - dsst);
            float varp = (ss_p - sum_p * sum_p * (1.0f / WLEN)) * (1.0f / (WLEN - 1));
            float vart = (ss_t - sum_t * sum_t * (1.0f / WLEN)) * (1.0f / (WLEN - 1));
            float stdp = sqrtf(fmaxf(varp, 0.f));
            float stdt = sqrtf(fmaxf(vart, 0.f));
            float kappa = 100.0f + (99900.0f / 48000.0f) * (float)(l0 + i);
            kl2s[i] = kappa * LOG2E;
            cps[i]  = stdp * LOG2E;
            cts[i]  = stdt * LOG2E;
            mxl = fmaxf(mxl, fmaxf(stdp, stdt));
            base_sp  += rl63(isp);
            base_ssp += rl63(issp);
            base_st  += rl63(ist);
            base_sst += rl63(isst);
        }
        float mx = wave_max_bcast(mxl);
        if (lane == 0) {
            float kmin = 100.0f + (99900.0f / 48000.0f) * (float)l0;
            // tap escapes saturation iff |v| <= (std + 24*ln2)/kappa ; superset
            tsh = (mx + 17.0f) * 1.001f / kmin;
        }
    } else if (wv == 1 && early) {
        float carry = 0.f;
#pragma unroll
        for (int h = 0; h < 2; ++h) {
            int kk = n_min + 64 * h + lane;
            float wval = (kk <= 1024) ? win[kk] : 0.f;
            float I = wave_scan_incl(wval) + carry;   // I[m] = sum w[n_min..n_min+m]
            iw[64 * h + lane] = I;
            carry = rl63(I);
        }
    }
    __syncthreads();

    // ---- Phase D: candidate compaction (samples that can escape saturation)
    {
        const float T = tsh;
        const int npad = early ? (1025 - l0) : 0;
        for (int j = tid; j < JMAX; j += THREADS) {
            bool flag = (j >= npad) &&
                        ((fabsf(segp[j + 3]) <= T) || (fabsf(segt[j + 3]) <= T));
            unsigned long long m = __ballot(flag);
            int cnt = __popcll(m);
            int base = 0;
            if (lane == 0 && cnt) base = atomicAdd(&ncand_sh, cnt);
            base = __shfl(base, 0);
            if (flag) {
                int pos = base + __popcll(m & ((1ull << lane) - 1ull));
                cand[pos] = j;
            }
        }
    }
    __syncthreads();

    // ---- Phase E: correction sweep; lane owns frames A=lane, B=lane+64
    const float kl2A = kl2s[lane],      cpA = cps[lane],      ctA = cts[lane];
    const float kl2B = kl2s[lane + 64], cpB = cps[lane + 64], ctB = cts[lane + 64];
    float aPA = 0.f, aTA = 0.f, aPB = 0.f, aTB = 0.f;   // sum of (sigma-1)*w
    const int nc = ncand_sh;
    for (int c = wv; c < nc; c += WAVES) {
        int j = cand[c];                        // wave-uniform LDS broadcast
        float avp = fabsf(segp[j + 3]), avt = fabsf(segt[j + 3]);
        int kA = j - lane;                      // tap index for frame A
        if ((unsigned)kA < 1025u) {
            float wk = win[kA];                 // stride-1 across lanes, L1-hit
            aPA = fmaf(sigm1(fmaf(-avp, kl2A, cpA)), wk, aPA);
            aTA = fmaf(sigm1(fmaf(-avt, kl2A, ctA)), wk, aTA);
        }
        int kB = kA - 64;                       // tap index for frame B
        if ((unsigned)kB < 1025u) {
            float wk = win[kB];
            aPB = fmaf(sigm1(fmaf(-avp, kl2B, cpB)), wk, aPB);
            aTB = fmaf(sigm1(fmaf(-avt, kl2B, ctB)), wk, aTB);
        }
    }
    partp[wv][lane]      = aPA;
    partp[wv][lane + 64] = aPB;
    partt[wv][lane]      = aTA;
    partt[wv][lane + 64] = aTB;
    __syncthreads();

    // ---- Phase F: combine, add pad term, square differences -> per-block partial
    if (wv < 2) {
        int i = lane + 64 * wv;
        float SP = 0.f, ST = 0.f;
#pragma unroll
        for (int w = 0; w < WAVES; ++w) {
            SP += partp[w][i];
            ST += partt[w][i];
        }
        if (early) {
            float padbase = 0.f;
#pragma unroll
            for (int w = 0; w < WAVES; ++w) padbase += redv[w][4];
            int n_f = 1025 - l0 - i;            // zero-pad tap count for frame l0+i
            float pw = 0.f;
            if (n_f >= 1) {
                int lf = n_f - n_min;           // in [0, 127]
                pw = padbase + ((lf >= 1) ? iw[lf - 1] : 0.f);
            }
            SP = fmaf(sigm1(cps[i]), pw, SP);   // v = 0 taps: a = std*log2e
            ST = fmaf(sigm1(cts[i]), pw, ST);
        }
        float d  = SP - ST;                     // window-sum term cancels exactly
        float dd = wave_sum_bcast(d * d);
        if (lane == 0) ddsh[wv] = dd;
    }
    __syncthreads();
    if (tid == 0) wsbuf[blockIdx.x] = ddsh[0] + ddsh[1];   // plain store, no atomics
}

// Deterministic final reduction: 1 block, reads NBLK partials, writes out.
__global__ __launch_bounds__(THREADS) void soft_edp_reduce(
    const float* __restrict__ wsbuf, float* __restrict__ out)
{
    __shared__ float acc[WAVES];
    const int tid = threadIdx.x, lane = tid & 63, wv = tid >> 6;
    float v = (tid < NBLK) ? wsbuf[tid] : 0.f;
    v = wave_sum_bcast(v);
    if (lane == 0) acc[wv] = v;
    __syncthreads();
    if (tid == 0) {
        float t = 0.f;
#pragma unroll
        for (int w = 0; w < WAVES; ++w) t += acc[w];
        const float scale =
            (float)(1.0 / (48000.0 * 0.3173105078629141 * 0.3173105078629141));
        out[0] = t * scale;                     // unconditional write: no memset needed
    }
}

extern "C" void kernel_launch(void* const* d_in, const int* in_sizes, int n_in,
                              void* d_out, int out_size, void* d_ws, size_t ws_size,
                              hipStream_t stream) {
    const float* xp  = (const float*)d_in[0];  // y_pred, 48000 f32
    const float* xt  = (const float*)d_in[1];  // y_true, 48000 f32
    const float* win = (const float*)d_in[2];  // window, 1025 f32
    float* out = (float*)d_out;
    float* wsb = (float*)d_ws;                 // NBLK f32 partials (overwritten each call)

    soft_edp_kernel<<<NBLK, THREADS, 0, stream>>>(xp, xt, win, wsb);
    soft_edp_reduce<<<1, THREADS, 0, stream>>>(wsb, out);
}